// Round 3
// baseline (459.140 us; speedup 1.0000x reference)
//
#include <hip/hip_runtime.h>
#include <stdint.h>

#define GENOMES 8
#define BATCH 2
#define SEQ 2048
#define EMBED 1024
#define KVD 256              // KV_HEADS * HEAD_DIM
#define M_PER_G (BATCH*SEQ)  // 4096

typedef float f32x4 __attribute__((ext_vector_type(4)));
typedef __bf16 bf16x8 __attribute__((ext_vector_type(8)));
typedef short s16x8 __attribute__((ext_vector_type(8)));
typedef short s16x4 __attribute__((ext_vector_type(4)));

static __device__ __forceinline__ unsigned short f2bf(float f) {
  unsigned int u = __builtin_bit_cast(unsigned int, f);
  u += 0x7FFFu + ((u >> 16) & 1u);   // round-to-nearest-even
  return (unsigned short)(u >> 16);
}

// ---------------------------------------------------------------------------
// Wv (g, 1024, 256) fp32  ->  WvT (g, 256, 1024) bf16   (B^T layout for GEMM1)
// ---------------------------------------------------------------------------
__global__ __launch_bounds__(256) void wvt_kernel(const float* __restrict__ Wv,
                                                  unsigned short* __restrict__ WvT) {
  int g = blockIdx.y;
  int it = blockIdx.x >> 2;          // 16 i-tiles of 64
  int ot = blockIdx.x & 3;           // 4 o-tiles of 64
  int i0 = it * 64, o0 = ot * 64;
  const float* W = Wv + (size_t)g * EMBED * KVD;
  unsigned short* T = WvT + (size_t)g * KVD * EMBED;
  __shared__ unsigned short tl[64][65];
  int t = threadIdx.x;
  int rr = t >> 4;            // 0..15
  int cc = (t & 15) * 4;      // 0..60
#pragma unroll
  for (int p = 0; p < 4; ++p) {
    int r = rr + p * 16;
    float4 v = *(const float4*)(W + (size_t)(i0 + r) * KVD + o0 + cc);
    tl[r][cc + 0] = f2bf(v.x);
    tl[r][cc + 1] = f2bf(v.y);
    tl[r][cc + 2] = f2bf(v.z);
    tl[r][cc + 3] = f2bf(v.w);
  }
  __syncthreads();
#pragma unroll
  for (int p = 0; p < 4; ++p) {
    int o = rr + p * 16;
    s16x4 v;
    v[0] = (short)tl[cc + 0][o];
    v[1] = (short)tl[cc + 1][o];
    v[2] = (short)tl[cc + 2][o];
    v[3] = (short)tl[cc + 3][o];
    *(s16x4*)(T + (size_t)(o0 + o) * EMBED + i0 + cc) = v;
  }
}

// ---------------------------------------------------------------------------
// Wo (g, 1024, 1024) fp32 -> RT (g, 1024, 256) bf16
// RT[o][kh*64+d] = 64 * sum_{r=0..3} Wo[kh*256 + r*64 + d][o]
// ---------------------------------------------------------------------------
__global__ __launch_bounds__(256) void rt_kernel(const float* __restrict__ Wo,
                                                 unsigned short* __restrict__ RT) {
  int g = blockIdx.y;
  int ot = blockIdx.x >> 2;          // 16 o-tiles of 64
  int kh = blockIdx.x & 3;           // 4 kv heads
  int o0 = ot * 64;
  const float* W = Wo + (size_t)g * EMBED * EMBED;
  unsigned short* T = RT + (size_t)g * EMBED * KVD;
  __shared__ float tl[64][65];
  int t = threadIdx.x;
  int rr = t >> 4;
  int cc = (t & 15) * 4;
#pragma unroll
  for (int p = 0; p < 4; ++p) {
    int d = rr + p * 16;
    float a0 = 0.f, a1 = 0.f, a2 = 0.f, a3 = 0.f;
#pragma unroll
    for (int r = 0; r < 4; ++r) {
      float4 v = *(const float4*)(W + (size_t)(kh * 256 + r * 64 + d) * EMBED + o0 + cc);
      a0 += v.x; a1 += v.y; a2 += v.z; a3 += v.w;
    }
    tl[d][cc + 0] = a0; tl[d][cc + 1] = a1; tl[d][cc + 2] = a2; tl[d][cc + 3] = a3;
  }
  __syncthreads();
#pragma unroll
  for (int p = 0; p < 4; ++p) {
    int o = rr + p * 16;
    s16x4 v;
    v[0] = (short)f2bf(64.f * tl[cc + 0][o]);
    v[1] = (short)f2bf(64.f * tl[cc + 1][o]);
    v[2] = (short)f2bf(64.f * tl[cc + 2][o]);
    v[3] = (short)f2bf(64.f * tl[cc + 3][o]);
    *(s16x4*)(T + (size_t)(o0 + o) * KVD + kh * 64 + cc) = v;
  }
}

// ---------------------------------------------------------------------------
// LDS-free, barrier-free GEMM:  C[M,N] = A[M,K] * Bt[N,K]^T  per genome.
// Block = 4 waves sharing one 64-row m-strip (A re-read served by L1);
// wave w owns a private 64x64 output tile at n = bn*256 + w*64.
// MFMA fragments are loaded DIRECTLY from global (B^T layout makes both
// A and B fragments contiguous 16-32 B per lane), double-buffered in
// registers -> loads for tile k+1 are in flight during MFMA of tile k,
// with partial vmcnt waits (no vmcnt(0) drain, no s_barrier anywhere).
// ---------------------------------------------------------------------------
template <bool A_F32, bool OUT_BF16, int N, int K>
__global__ __launch_bounds__(256) void gemm_direct(const void* __restrict__ Aall,
                                                   const unsigned short* __restrict__ Btall,
                                                   void* __restrict__ Call) {
  constexpr int BK = 32;
  constexpr int NKT = K / BK;
  constexpr int NG = N / 256;        // n-groups of 256 (4 waves x 64)

  int g = blockIdx.y;
  int bm = blockIdx.x / NG;
  int bn = blockIdx.x % NG;          // bn fastest -> same-m blocks adjacent (L2/L1 reuse of A)
  int m0 = bm * 64;

  int t = threadIdx.x;
  int lane = t & 63, wave = t >> 6;
  int n0 = bn * 256 + wave * 64;
  int lm = lane & 15, quad = lane >> 4;
  int kq = quad * 8;

  const float* Af = (const float*)Aall + (size_t)g * M_PER_G * K + (size_t)(m0 + lm) * K + kq;
  const unsigned short* Ab = (const unsigned short*)Aall + (size_t)g * M_PER_G * K + (size_t)(m0 + lm) * K + kq;
  const unsigned short* Bt = Btall + (size_t)g * N * K + (size_t)(n0 + lm) * K + kq;

  f32x4 acc[4][4] = {};

  // register double-buffers for fragments
  float4 a0f[4][2], a1f[4][2];
  s16x8 a0b[4], a1b[4];
  s16x8 b0[4], b1[4];

  auto loadA = [&](int k0, float4 af[4][2], s16x8 ab[4]) {
    if constexpr (A_F32) {
#pragma unroll
      for (int i = 0; i < 4; ++i) {
        const float* p = Af + (size_t)(i * 16) * K + k0;
        af[i][0] = *(const float4*)p;
        af[i][1] = *(const float4*)(p + 4);
      }
    } else {
#pragma unroll
      for (int i = 0; i < 4; ++i)
        ab[i] = *(const s16x8*)(Ab + (size_t)(i * 16) * K + k0);
    }
  };
  auto loadB = [&](int k0, s16x8 b[4]) {
#pragma unroll
    for (int j = 0; j < 4; ++j)
      b[j] = *(const s16x8*)(Bt + (size_t)(j * 16) * K + k0);
  };
  auto step = [&](float4 af[4][2], s16x8 ab[4], s16x8 b[4]) {
    bf16x8 abf[4], bbf[4];
#pragma unroll
    for (int i = 0; i < 4; ++i) {
      if constexpr (A_F32) {
        bf16x8 c;
        c[0] = (__bf16)af[i][0].x; c[1] = (__bf16)af[i][0].y;
        c[2] = (__bf16)af[i][0].z; c[3] = (__bf16)af[i][0].w;
        c[4] = (__bf16)af[i][1].x; c[5] = (__bf16)af[i][1].y;
        c[6] = (__bf16)af[i][1].z; c[7] = (__bf16)af[i][1].w;
        abf[i] = c;
      } else {
        abf[i] = __builtin_bit_cast(bf16x8, ab[i]);
      }
      bbf[i] = __builtin_bit_cast(bf16x8, b[i]);
    }
#pragma unroll
    for (int i = 0; i < 4; ++i)
#pragma unroll
      for (int j = 0; j < 4; ++j)
        acc[i][j] = __builtin_amdgcn_mfma_f32_16x16x32_bf16(abf[i], bbf[j], acc[i][j], 0, 0, 0);
  };

  loadA(0, a0f, a0b);
  loadB(0, b0);
  for (int kt = 0; kt < NKT; kt += 2) {
    int k1 = (kt + 1 < NKT ? kt + 1 : NKT - 1) * BK;
    loadA(k1, a1f, a1b);             // in flight during step(buf0)
    loadB(k1, b1);
    step(a0f, a0b, b0);
    int k2 = (kt + 2 < NKT ? kt + 2 : NKT - 1) * BK;
    loadA(k2, a0f, a0b);             // in flight during step(buf1)
    loadB(k2, b0);
    step(a1f, a1b, b1);
  }

  // ---- epilogue: C/D layout col=lane&15, row=quad*4+reg ----
  if constexpr (OUT_BF16) {
    unsigned short* C = (unsigned short*)Call + (size_t)g * M_PER_G * N;
#pragma unroll
    for (int i = 0; i < 4; ++i)
#pragma unroll
      for (int j = 0; j < 4; ++j)
#pragma unroll
        for (int r = 0; r < 4; ++r) {
          int mm = m0 + i * 16 + quad * 4 + r;
          int nn = n0 + j * 16 + lm;
          C[(size_t)mm * N + nn] = f2bf(acc[i][j][r]);
        }
  } else {
    float* C = (float*)Call + (size_t)g * M_PER_G * N;
#pragma unroll
    for (int i = 0; i < 4; ++i)
#pragma unroll
      for (int j = 0; j < 4; ++j)
#pragma unroll
        for (int r = 0; r < 4; ++r) {
          int mm = m0 + i * 16 + quad * 4 + r;
          int nn = n0 + j * 16 + lm;
          __builtin_nontemporal_store(acc[i][j][r], C + (size_t)mm * N + nn);
        }
  }
}

// ---------------------------------------------------------------------------
extern "C" void kernel_launch(void* const* d_in, const int* in_sizes, int n_in,
                              void* d_out, int out_size, void* d_ws, size_t ws_size,
                              hipStream_t stream) {
  const float* tensor = (const float*)d_in[0];
  // d_in[1] = Wq, d_in[2] = Wk: dead code in the reference (einsum contracts them out)
  const float* Wv = (const float*)d_in[3];
  const float* Wo = (const float*)d_in[4];
  float* out = (float*)d_out;

  unsigned short* WvT = (unsigned short*)d_ws;                       //  4 MB
  unsigned short* RT  = WvT + (size_t)GENOMES * KVD * EMBED;         //  4 MB
  unsigned short* V   = RT  + (size_t)GENOMES * EMBED * KVD;         // 16 MB

  wvt_kernel<<<dim3(64, GENOMES), 256, 0, stream>>>(Wv, WvT);
  rt_kernel<<<dim3(64, GENOMES), 256, 0, stream>>>(Wo, RT);

  // GEMM1: V[g] (4096x256 bf16) = tensor[g] (4096x1024 fp32->bf16) @ WvT^T
  // grid: 64 m-strips x 8 genomes, 1 n-group (N=256 = 4 waves x 64)
  gemm_direct<true, true, KVD, EMBED>
      <<<dim3(M_PER_G / 64, GENOMES), 256, 0, stream>>>(tensor, WvT, V);

  // GEMM2: out[g] (4096x1024 fp32) = V[g] (4096x256 bf16) @ RT^T (x64 folded in RT)
  // grid: 64 m-strips x 4 n-groups x 8 genomes
  gemm_direct<false, false, EMBED, KVD>
      <<<dim3((M_PER_G / 64) * (EMBED / 256), GENOMES), 256, 0, stream>>>(V, RT, out);
}